// Round 1
// baseline (864.214 us; speedup 1.0000x reference)
//
#include <hip/hip_runtime.h>
#include <stdint.h>

#define LEN_T 13294
#define M_TOK 53176   // 4 * 13294

typedef unsigned short u16;
typedef __bf16 bf16x8 __attribute__((ext_vector_type(8)));
typedef float f32x4 __attribute__((ext_vector_type(4)));

__device__ __forceinline__ u16 f2bf(float f) {
    union { float f; uint32_t u; } v; v.f = f;
    uint32_t r = v.u + 0x7fffu + ((v.u >> 16) & 1u);
    return (u16)(r >> 16);
}
__device__ __forceinline__ float bf2f(u16 s) {
    union { uint32_t u; float f; } v; v.u = ((uint32_t)s) << 16;
    return v.f;
}
__device__ __forceinline__ float blo(uint32_t u) {
    union { uint32_t u; float f; } v; v.u = u << 16; return v.f;
}
__device__ __forceinline__ float bhi(uint32_t u) {
    union { uint32_t u; float f; } v; v.u = u & 0xffff0000u; return v.f;
}

// ---------------- prep: q = bf16(features+pos), f = bf16(features) -------------
__global__ __launch_bounds__(256) void prep_qf(
    const float* __restrict__ feat, const float* __restrict__ pos,
    u16* __restrict__ qb, u16* __restrict__ fb, int n4)
{
    int i = blockIdx.x * blockDim.x + threadIdx.x;
    int stride = gridDim.x * blockDim.x;
    for (; i < n4; i += stride) {
        float4 f = ((const float4*)feat)[i];
        float4 p = ((const float4*)pos)[i];
        uint32_t q0 = (uint32_t)f2bf(f.x + p.x) | ((uint32_t)f2bf(f.y + p.y) << 16);
        uint32_t q1 = (uint32_t)f2bf(f.z + p.z) | ((uint32_t)f2bf(f.w + p.w) << 16);
        uint32_t f0 = (uint32_t)f2bf(f.x) | ((uint32_t)f2bf(f.y) << 16);
        uint32_t f1 = (uint32_t)f2bf(f.z) | ((uint32_t)f2bf(f.w) << 16);
        ((uint2*)qb)[i] = make_uint2(q0, q1);
        ((uint2*)fb)[i] = make_uint2(f0, f1);
    }
}

// ---------------- weight transpose to (N x K) bf16 -----------------------------
__global__ __launch_bounds__(256) void wtrans(
    const float* __restrict__ W, u16* __restrict__ Wt, int K, int N)
{
    int gid = blockIdx.x * blockDim.x + threadIdx.x;
    if (gid >= K * N) return;
    int n = gid / K, k = gid - n * K;
    Wt[gid] = f2bf(W[(size_t)k * N + n]);
}

// ---------------- generic 64x64-tile MFMA GEMM with fused epilogues ------------
#define MODE_VAL 0
#define MODE_OFFATTN 1
#define MODE_OUT 2
#define MODE_FFN1 3
#define MODE_FFN2 4

template<int MODE>
__global__ __launch_bounds__(256, 2) void gemm64(
    const u16* __restrict__ A, const u16* __restrict__ Bt,
    int M, int K, int nb_per_group,
    const float* __restrict__ bias, const float* __restrict__ bias2,
    const float* __restrict__ resf, const u16* __restrict__ resbf,
    void* __restrict__ out0, void* __restrict__ out1)
{
    extern __shared__ u16 smem[];
    u16* Al = smem;              // [64][264]
    u16* Bl = smem + 64 * 264;   // [64][264]
    const int tid = threadIdx.x;
    const int lane = tid & 63;
    const int w = tid >> 6;
    const int wr = w >> 1, wc = w & 1;
    const int m0 = blockIdx.x * 64;
    const int l15 = lane & 15;
    const int kg = lane >> 4;
    const int kchunks = K >> 8;

    for (int jb = 0; jb < nb_per_group; ++jb) {
        const int n0 = (blockIdx.y * nb_per_group + jb) * 64;
        f32x4 zero = {0.f, 0.f, 0.f, 0.f};
        f32x4 acc[2][2];
        acc[0][0] = zero; acc[0][1] = zero; acc[1][0] = zero; acc[1][1] = zero;

        for (int kc = 0; kc < kchunks; ++kc) {
            __syncthreads();
#pragma unroll
            for (int i = 0; i < 8; ++i) {
                int linear = i * 256 + tid;
                int row = linear >> 5;     // 32 x 16B chunks per 256-elem row
                int c8 = linear & 31;
                int grow = m0 + row;
                grow = grow < M ? grow : M - 1;
                uint4 va = *(const uint4*)(A + (size_t)grow * K + (kc << 8) + c8 * 8);
                *(uint4*)(Al + row * 264 + c8 * 8) = va;
                uint4 vb = *(const uint4*)(Bt + (size_t)(n0 + row) * K + (kc << 8) + c8 * 8);
                *(uint4*)(Bl + row * 264 + c8 * 8) = vb;
            }
            __syncthreads();
#pragma unroll
            for (int ks = 0; ks < 8; ++ks) {
                bf16x8 a0 = *(const bf16x8*)(Al + (wr * 32 + l15) * 264 + ks * 32 + kg * 8);
                bf16x8 a1 = *(const bf16x8*)(Al + (wr * 32 + 16 + l15) * 264 + ks * 32 + kg * 8);
                bf16x8 b0 = *(const bf16x8*)(Bl + (wc * 32 + l15) * 264 + ks * 32 + kg * 8);
                bf16x8 b1 = *(const bf16x8*)(Bl + (wc * 32 + 16 + l15) * 264 + ks * 32 + kg * 8);
                acc[0][0] = __builtin_amdgcn_mfma_f32_16x16x32_bf16(a0, b0, acc[0][0], 0, 0, 0);
                acc[0][1] = __builtin_amdgcn_mfma_f32_16x16x32_bf16(a0, b1, acc[0][1], 0, 0, 0);
                acc[1][0] = __builtin_amdgcn_mfma_f32_16x16x32_bf16(a1, b0, acc[1][0], 0, 0, 0);
                acc[1][1] = __builtin_amdgcn_mfma_f32_16x16x32_bf16(a1, b1, acc[1][1], 0, 0, 0);
            }
        }
        // epilogue: C/D layout col = lane&15, row = (lane>>4)*4 + reg
#pragma unroll
        for (int mi = 0; mi < 2; ++mi) {
#pragma unroll
            for (int r = 0; r < 4; ++r) {
                int row = m0 + wr * 32 + mi * 16 + kg * 4 + r;
                if (row >= M) continue;
#pragma unroll
                for (int ni = 0; ni < 2; ++ni) {
                    int col = n0 + wc * 32 + ni * 16 + l15;
                    float v = acc[mi][ni][r];
                    if (MODE == MODE_VAL) {
                        int bI = row / LEN_T;
                        int t = row - bI * LEN_T;
                        int hh = col >> 5, d = col & 31;
                        ((u16*)out0)[((size_t)(bI * 8 + hh) * LEN_T + t) * 32 + d] =
                            f2bf(v + bias[col]);
                    } else if (MODE == MODE_OFFATTN) {
                        if (col < 256)
                            ((float*)out0)[(size_t)row * 256 + col] = v + bias[col];
                        else
                            ((float*)out1)[(size_t)row * 128 + (col - 256)] = v + bias2[col - 256];
                    } else if (MODE == MODE_OUT) {
                        ((float*)out0)[(size_t)row * 256 + col] =
                            v + bias[col] + resf[(size_t)row * 256 + col];
                    } else if (MODE == MODE_FFN1) {
                        float x = v + bias[col];
                        ((u16*)out0)[(size_t)row * 1024 + col] = f2bf(x > 0.f ? x : 0.f);
                    } else { // MODE_FFN2
                        ((float*)out0)[(size_t)row * 256 + col] =
                            v + bias[col] + bf2f(resbf[(size_t)row * 256 + col]);
                    }
                }
            }
        }
    }
}

// ---------------- deformable sampling ------------------------------------------
__device__ __forceinline__ void corner_acc(const u16* __restrict__ vb, int xi, int yi,
                                           int W_, int H_, float w, float* acc)
{
    if (xi < 0 || xi >= W_ || yi < 0 || yi >= H_) return;
    const uint4* p = (const uint4*)(vb + ((size_t)(yi * W_ + xi)) * 32);
#pragma unroll
    for (int i = 0; i < 4; ++i) {
        uint4 v = p[i];
        acc[i*8+0] = fmaf(w, blo(v.x), acc[i*8+0]);
        acc[i*8+1] = fmaf(w, bhi(v.x), acc[i*8+1]);
        acc[i*8+2] = fmaf(w, blo(v.y), acc[i*8+2]);
        acc[i*8+3] = fmaf(w, bhi(v.y), acc[i*8+3]);
        acc[i*8+4] = fmaf(w, blo(v.z), acc[i*8+4]);
        acc[i*8+5] = fmaf(w, bhi(v.z), acc[i*8+5]);
        acc[i*8+6] = fmaf(w, blo(v.w), acc[i*8+6]);
        acc[i*8+7] = fmaf(w, bhi(v.w), acc[i*8+7]);
    }
}

__global__ __launch_bounds__(256) void sample_kernel(
    const float* __restrict__ offb, const float* __restrict__ attnb,
    const u16* __restrict__ value, const float* __restrict__ refp,
    u16* __restrict__ samp)
{
    int gid = blockIdx.x * blockDim.x + threadIdx.x;
    if (gid >= M_TOK * 8) return;
    int h = gid & 7;
    int tok = gid >> 3;
    int b = tok / LEN_T;

    // softmax over 16 logits
    const float* ap = attnb + (size_t)tok * 128 + h * 16;
    float aw[16];
#pragma unroll
    for (int i = 0; i < 4; ++i) {
        float4 v = ((const float4*)ap)[i];
        aw[4*i+0] = v.x; aw[4*i+1] = v.y; aw[4*i+2] = v.z; aw[4*i+3] = v.w;
    }
    float mx = -1e30f;
#pragma unroll
    for (int i = 0; i < 16; ++i) mx = fmaxf(mx, aw[i]);
    float ssum = 0.f;
#pragma unroll
    for (int i = 0; i < 16; ++i) { aw[i] = __expf(aw[i] - mx); ssum += aw[i]; }
    float inv = 1.0f / ssum;
#pragma unroll
    for (int i = 0; i < 16; ++i) aw[i] *= inv;

    float acc[32];
#pragma unroll
    for (int d = 0; d < 32; ++d) acc[d] = 0.f;

    const float* op = offb + (size_t)tok * 256 + h * 32;
    const float* rp = refp + (size_t)tok * 8;

    const int Wl[4] = {100, 50, 25, 13};
    const int Sl[4] = {0, 10000, 12500, 13125};

#pragma unroll
    for (int l = 0; l < 4; ++l) {
        const int W_ = Wl[l];
        const int H_ = Wl[l];
        const float Wf = (float)W_;
        const float invW = 1.0f / Wf;
        const u16* vb = value + ((size_t)(b * 8 + h) * LEN_T + Sl[l]) * 32;
        float rx = rp[l*2+0], ry = rp[l*2+1];
#pragma unroll
        for (int p = 0; p < 4; ++p) {
            float dx = op[l*8 + p*2 + 0];
            float dy = op[l*8 + p*2 + 1];
            float x = fmaf(fmaf(dx, invW, rx), Wf, -0.5f);
            float y = fmaf(fmaf(dy, invW, ry), Wf, -0.5f);
            float x0f = floorf(x), y0f = floorf(y);
            int x0 = (int)x0f, y0 = (int)y0f;
            float wx = x - x0f, wy = y - y0f;
            float a = aw[l*4+p];
            float w00 = (1.f-wx)*(1.f-wy)*a;
            float w10 = wx*(1.f-wy)*a;
            float w01 = (1.f-wx)*wy*a;
            float w11 = wx*wy*a;
            corner_acc(vb, x0,   y0,   W_, H_, w00, acc);
            corner_acc(vb, x0+1, y0,   W_, H_, w10, acc);
            corner_acc(vb, x0,   y0+1, W_, H_, w01, acc);
            corner_acc(vb, x0+1, y0+1, W_, H_, w11, acc);
        }
    }
    uint32_t u[16];
#pragma unroll
    for (int i = 0; i < 16; ++i)
        u[i] = (uint32_t)f2bf(acc[2*i]) | ((uint32_t)f2bf(acc[2*i+1]) << 16);
    uint4* sp = (uint4*)(samp + (size_t)tok * 256 + h * 32);
#pragma unroll
    for (int i = 0; i < 4; ++i)
        sp[i] = make_uint4(u[4*i], u[4*i+1], u[4*i+2], u[4*i+3]);
}

// ---------------- LayerNorm (wave per row of 256) ------------------------------
template<int WRITE_BF16>
__global__ __launch_bounds__(256) void ln_kernel(
    const float* __restrict__ in, const float* __restrict__ g, const float* __restrict__ bb,
    u16* __restrict__ outb, float* __restrict__ outf)
{
    int row = blockIdx.x * 4 + (threadIdx.x >> 6);
    int lane = threadIdx.x & 63;
    const float4 v = *(const float4*)(in + (size_t)row * 256 + lane * 4);
    float s = v.x + v.y + v.z + v.w;
#pragma unroll
    for (int o = 1; o < 64; o <<= 1) s += __shfl_xor(s, o);
    float mu = s * (1.0f / 256.0f);
    float d0 = v.x - mu, d1 = v.y - mu, d2 = v.z - mu, d3 = v.w - mu;
    float q = d0*d0 + d1*d1 + d2*d2 + d3*d3;
#pragma unroll
    for (int o = 1; o < 64; o <<= 1) q += __shfl_xor(q, o);
    float rs = rsqrtf(q * (1.0f / 256.0f) + 1e-5f);
    float4 gv = *(const float4*)(g + lane * 4);
    float4 bv = *(const float4*)(bb + lane * 4);
    float o0 = d0 * rs * gv.x + bv.x;
    float o1 = d1 * rs * gv.y + bv.y;
    float o2 = d2 * rs * gv.z + bv.z;
    float o3 = d3 * rs * gv.w + bv.w;
    if (WRITE_BF16) {
        uint32_t u0 = (uint32_t)f2bf(o0) | ((uint32_t)f2bf(o1) << 16);
        uint32_t u1 = (uint32_t)f2bf(o2) | ((uint32_t)f2bf(o3) << 16);
        *(uint2*)(outb + (size_t)row * 256 + lane * 4) = make_uint2(u0, u1);
    } else {
        *(float4*)(outf + (size_t)row * 256 + lane * 4) = make_float4(o0, o1, o2, o3);
    }
}

// ---------------- launcher -----------------------------------------------------
extern "C" void kernel_launch(void* const* d_in, const int* in_sizes, int n_in,
                              void* d_out, int out_size, void* d_ws, size_t ws_size,
                              hipStream_t stream)
{
    const float* features = (const float*)d_in[0];
    const float* pos      = (const float*)d_in[1];
    const float* refp     = (const float*)d_in[2];
    // d_in[3] spatial_shapes, d_in[4] lvl_start_idx: hardcoded
    const float* W_off  = (const float*)d_in[5];
    const float* b_off  = (const float*)d_in[6];
    const float* W_attn = (const float*)d_in[7];
    const float* b_attn = (const float*)d_in[8];
    const float* W_val  = (const float*)d_in[9];
    const float* b_val  = (const float*)d_in[10];
    const float* W_out  = (const float*)d_in[11];
    const float* b_out  = (const float*)d_in[12];
    const float* ln1_g  = (const float*)d_in[13];
    const float* ln1_b  = (const float*)d_in[14];
    const float* W1     = (const float*)d_in[15];
    const float* b1     = (const float*)d_in[16];
    const float* W2     = (const float*)d_in[17];
    const float* b2     = (const float*)d_in[18];
    const float* ln2_g  = (const float*)d_in[19];
    const float* ln2_b  = (const float*)d_in[20];
    float* out = (float*)d_out;

    char* ws = (char*)d_ws;
    size_t o = 0;
    auto alloc = [&](size_t bytes) { char* p = ws + o; o += (bytes + 255) & ~(size_t)255; return p; };
    u16* Wt_val = (u16*)alloc((size_t)256 * 256 * 2);
    u16* Wt_oa  = (u16*)alloc((size_t)384 * 256 * 2);
    u16* Wt_out = (u16*)alloc((size_t)256 * 256 * 2);
    u16* Wt1    = (u16*)alloc((size_t)1024 * 256 * 2);
    u16* Wt2    = (u16*)alloc((size_t)256 * 1024 * 2);
    u16* qb     = (u16*)alloc((size_t)M_TOK * 256 * 2);   // later reused as x_bf16
    u16* fb     = (u16*)alloc((size_t)M_TOK * 256 * 2);   // later reused as samp
    char* big   = alloc((size_t)M_TOK * 1024 * 2);        // value|off|attn, later h
    u16*   value = (u16*)big;
    float* offb  = (float*)(big + (size_t)M_TOK * 256 * 2);
    float* attnb = (float*)(big + (size_t)M_TOK * 256 * 2 + (size_t)M_TOK * 256 * 4);
    u16*   hbuf  = (u16*)big;
    u16* xb   = qb;
    u16* samp = fb;

    dim3 blk(256);
    const int mb = (M_TOK + 63) / 64;        // 831
    const size_t shmem = (size_t)2 * 64 * 264 * 2;  // 67584 B

    prep_qf<<<2048, blk, 0, stream>>>(features, pos, qb, fb, M_TOK * 256 / 4);
    wtrans<<<(256*256 + 255) / 256, blk, 0, stream>>>(W_val,  Wt_val, 256, 256);
    wtrans<<<(256*256 + 255) / 256, blk, 0, stream>>>(W_off,  Wt_oa,  256, 256);
    wtrans<<<(128*256 + 255) / 256, blk, 0, stream>>>(W_attn, Wt_oa + 256*256, 256, 128);
    wtrans<<<(256*256 + 255) / 256, blk, 0, stream>>>(W_out,  Wt_out, 256, 256);
    wtrans<<<(1024*256 + 255) / 256, blk, 0, stream>>>(W1, Wt1, 256, 1024);
    wtrans<<<(1024*256 + 255) / 256, blk, 0, stream>>>(W2, Wt2, 1024, 256);

    gemm64<MODE_VAL><<<dim3(mb, 2), blk, shmem, stream>>>(
        fb, Wt_val, M_TOK, 256, 2, b_val, nullptr, nullptr, nullptr, value, nullptr);
    gemm64<MODE_OFFATTN><<<dim3(mb, 3), blk, shmem, stream>>>(
        qb, Wt_oa, M_TOK, 256, 2, b_off, b_attn, nullptr, nullptr, offb, attnb);

    sample_kernel<<<(M_TOK * 8 + 255) / 256, blk, 0, stream>>>(offb, attnb, value, refp, samp);

    gemm64<MODE_OUT><<<dim3(mb, 2), blk, shmem, stream>>>(
        samp, Wt_out, M_TOK, 256, 2, b_out, nullptr, features, nullptr, out, nullptr);

    ln_kernel<1><<<M_TOK / 4, blk, 0, stream>>>(out, ln1_g, ln1_b, xb, nullptr);

    gemm64<MODE_FFN1><<<dim3(mb, 4), blk, shmem, stream>>>(
        xb, Wt1, M_TOK, 256, 4, b1, nullptr, nullptr, nullptr, hbuf, nullptr);
    gemm64<MODE_FFN2><<<dim3(mb, 2), blk, shmem, stream>>>(
        hbuf, Wt2, M_TOK, 1024, 2, b2, nullptr, nullptr, xb, out, nullptr);

    ln_kernel<0><<<M_TOK / 4, blk, 0, stream>>>(out, ln2_g, ln2_b, nullptr, out);
}

// Round 2
// 566.390 us; speedup vs baseline: 1.5258x; 1.5258x over previous
//
#include <hip/hip_runtime.h>
#include <stdint.h>

#define LEN_T 13294
#define M_TOK 53176   // 4 * 13294

typedef unsigned short u16;
typedef __bf16 bf16x8 __attribute__((ext_vector_type(8)));
typedef float f32x4 __attribute__((ext_vector_type(4)));

__device__ __forceinline__ u16 f2bf(float f) {
    union { float f; uint32_t u; } v; v.f = f;
    uint32_t r = v.u + 0x7fffu + ((v.u >> 16) & 1u);
    return (u16)(r >> 16);
}
__device__ __forceinline__ float bf2f(u16 s) {
    union { uint32_t u; float f; } v; v.u = ((uint32_t)s) << 16;
    return v.f;
}
__device__ __forceinline__ float blo(uint32_t u) {
    union { uint32_t u; float f; } v; v.u = u << 16; return v.f;
}
__device__ __forceinline__ float bhi(uint32_t u) {
    union { uint32_t u; float f; } v; v.u = u & 0xffff0000u; return v.f;
}

__device__ __forceinline__ void gload_lds16(const u16* g, u16* l) {
    __builtin_amdgcn_global_load_lds(
        (const __attribute__((address_space(1))) uint32_t*)(g),
        (__attribute__((address_space(3))) uint32_t*)(l), 16, 0, 0);
}

// ---------------- prep: q = bf16(features+pos), f = bf16(features) -------------
__global__ __launch_bounds__(256) void prep_qf(
    const float* __restrict__ feat, const float* __restrict__ pos,
    u16* __restrict__ qb, u16* __restrict__ fb, int n4)
{
    int i = blockIdx.x * blockDim.x + threadIdx.x;
    int stride = gridDim.x * blockDim.x;
    for (; i < n4; i += stride) {
        float4 f = ((const float4*)feat)[i];
        float4 p = ((const float4*)pos)[i];
        uint32_t q0 = (uint32_t)f2bf(f.x + p.x) | ((uint32_t)f2bf(f.y + p.y) << 16);
        uint32_t q1 = (uint32_t)f2bf(f.z + p.z) | ((uint32_t)f2bf(f.w + p.w) << 16);
        uint32_t f0 = (uint32_t)f2bf(f.x) | ((uint32_t)f2bf(f.y) << 16);
        uint32_t f1 = (uint32_t)f2bf(f.z) | ((uint32_t)f2bf(f.w) << 16);
        ((uint2*)qb)[i] = make_uint2(q0, q1);
        ((uint2*)fb)[i] = make_uint2(f0, f1);
    }
}

// ---------------- all weight transposes to (N x K) bf16, one launch ------------
__global__ __launch_bounds__(256) void wtrans_all(
    const float* __restrict__ W_val, const float* __restrict__ W_off,
    const float* __restrict__ W_attn, const float* __restrict__ W_out,
    const float* __restrict__ W1, const float* __restrict__ W2,
    u16* __restrict__ Wt_val, u16* __restrict__ Wt_oa,
    u16* __restrict__ Wt_out, u16* __restrict__ Wt1, u16* __restrict__ Wt2)
{
    int gid = blockIdx.x * 256 + threadIdx.x;
    const float* W; u16* D; int K, N, off;
    if      (gid < 65536)  { W = W_val;  D = Wt_val;        K = 256;  N = 256;  off = gid; }
    else if (gid < 131072) { W = W_off;  D = Wt_oa;         K = 256;  N = 256;  off = gid - 65536; }
    else if (gid < 163840) { W = W_attn; D = Wt_oa + 65536; K = 256;  N = 128;  off = gid - 131072; }
    else if (gid < 229376) { W = W_out;  D = Wt_out;        K = 256;  N = 256;  off = gid - 163840; }
    else if (gid < 491520) { W = W1;     D = Wt1;           K = 256;  N = 1024; off = gid - 229376; }
    else if (gid < 753664) { W = W2;     D = Wt2;           K = 1024; N = 256;  off = gid - 491520; }
    else return;
    int n = off / K, k = off - n * K;
    D[off] = f2bf(W[(size_t)k * N + n]);
}

// ---------------- 128x128-tile MFMA GEMM (m97 structure) with fused epilogues --
#define MODE_VAL 0
#define MODE_OFFATTN 1
#define MODE_OUT 2
#define MODE_FFN1 3
#define MODE_FFN2 4

template<int MODE>
__global__ __launch_bounds__(256, 2) void gemm128(
    const u16* __restrict__ A, const u16* __restrict__ Bt,
    int M, int K,
    const float* __restrict__ bias, const float* __restrict__ bias2,
    const float* __restrict__ resf, const u16* __restrict__ resbf,
    void* __restrict__ out0, void* __restrict__ out1)
{
    __shared__ u16 Al[128 * 64];
    __shared__ u16 Bl[128 * 64];
    const int tid = threadIdx.x;
    const int lane = tid & 63;
    const int w = tid >> 6;
    const int wr = w >> 1, wc = w & 1;     // 2x2 wave grid, 64x64 per wave
    const int m0 = blockIdx.x * 128;
    const int n0 = blockIdx.y * 128;
    const int l15 = lane & 15;
    const int kg = lane >> 4;
    const int srow = lane >> 3;            // 0..7 within 8-row chunk
    const int scol = (lane & 7) * 8;       // 16B-aligned col

    f32x4 acc[4][4];
#pragma unroll
    for (int i = 0; i < 4; ++i)
#pragma unroll
        for (int j = 0; j < 4; ++j)
            acc[i][j] = (f32x4){0.f, 0.f, 0.f, 0.f};

    const int nk = K >> 6;
    for (int kc = 0; kc < nk; ++kc) {
        __syncthreads();
#pragma unroll
        for (int j = 0; j < 4; ++j) {
            int c = w * 4 + j;             // chunk 0..15, each 1KB (8 rows x 64 elems)
            int arow = m0 + c * 8 + srow;
            arow = arow < M ? arow : M - 1;
            gload_lds16(A + (size_t)arow * K + (kc << 6) + scol, Al + c * 512);
            int brow = n0 + c * 8 + srow;  // N is always a multiple of 128
            gload_lds16(Bt + (size_t)brow * K + (kc << 6) + scol, Bl + c * 512);
        }
        __syncthreads();
#pragma unroll
        for (int ks = 0; ks < 2; ++ks) {
            bf16x8 af[4], bfr[4];
#pragma unroll
            for (int i = 0; i < 4; ++i) {
                af[i]  = *(const bf16x8*)(Al + (wr * 64 + i * 16 + l15) * 64 + ks * 32 + kg * 8);
                bfr[i] = *(const bf16x8*)(Bl + (wc * 64 + i * 16 + l15) * 64 + ks * 32 + kg * 8);
            }
#pragma unroll
            for (int mi = 0; mi < 4; ++mi)
#pragma unroll
                for (int ni = 0; ni < 4; ++ni)
                    acc[mi][ni] = __builtin_amdgcn_mfma_f32_16x16x32_bf16(
                        af[mi], bfr[ni], acc[mi][ni], 0, 0, 0);
        }
    }

    // epilogue: C/D layout col = lane&15, row = (lane>>4)*4 + reg
#pragma unroll
    for (int mi = 0; mi < 4; ++mi) {
#pragma unroll
        for (int r = 0; r < 4; ++r) {
            int row = m0 + wr * 64 + mi * 16 + kg * 4 + r;
            if (row >= M) continue;
#pragma unroll
            for (int ni = 0; ni < 4; ++ni) {
                int col = n0 + wc * 64 + ni * 16 + l15;
                float v = acc[mi][ni][r];
                if (MODE == MODE_VAL) {
                    int bI = row / LEN_T;
                    int t = row - bI * LEN_T;
                    int hh = col >> 5, d = col & 31;
                    ((u16*)out0)[((size_t)(bI * 8 + hh) * LEN_T + t) * 32 + d] =
                        f2bf(v + bias[col]);
                } else if (MODE == MODE_OFFATTN) {
                    if (col < 256) {
                        // off transposed: [h][tok][32]
                        ((float*)out0)[((size_t)(col >> 5) * M_TOK + row) * 32 + (col & 31)] =
                            v + bias[col];
                    } else {
                        int c = col - 256;
                        // attn transposed: [h][tok][16]
                        ((float*)out1)[((size_t)(c >> 4) * M_TOK + row) * 16 + (c & 15)] =
                            v + bias2[c];
                    }
                } else if (MODE == MODE_OUT) {
                    ((float*)out0)[(size_t)row * 256 + col] =
                        v + bias[col] + resf[(size_t)row * 256 + col];
                } else if (MODE == MODE_FFN1) {
                    float x = v + bias[col];
                    ((u16*)out0)[(size_t)row * 1024 + col] = f2bf(x > 0.f ? x : 0.f);
                } else { // MODE_FFN2
                    ((float*)out0)[(size_t)row * 256 + col] =
                        v + bias[col] + bf2f(resbf[(size_t)row * 256 + col]);
                }
            }
        }
    }
}

// ---------------- deformable sampling ------------------------------------------
__device__ __forceinline__ void corner_acc(const u16* __restrict__ vb, int xi, int yi,
                                           int W_, int H_, float w, float* acc)
{
    if (xi < 0 || xi >= W_ || yi < 0 || yi >= H_) return;
    const uint4* p = (const uint4*)(vb + ((size_t)(yi * W_ + xi)) * 32);
#pragma unroll
    for (int i = 0; i < 4; ++i) {
        uint4 v = p[i];
        acc[i*8+0] = fmaf(w, blo(v.x), acc[i*8+0]);
        acc[i*8+1] = fmaf(w, bhi(v.x), acc[i*8+1]);
        acc[i*8+2] = fmaf(w, blo(v.y), acc[i*8+2]);
        acc[i*8+3] = fmaf(w, bhi(v.y), acc[i*8+3]);
        acc[i*8+4] = fmaf(w, blo(v.z), acc[i*8+4]);
        acc[i*8+5] = fmaf(w, bhi(v.z), acc[i*8+5]);
        acc[i*8+6] = fmaf(w, blo(v.w), acc[i*8+6]);
        acc[i*8+7] = fmaf(w, bhi(v.w), acc[i*8+7]);
    }
}

// one (b,h) group per run of 52 blocks; 256 consecutive tokens per block.
// XCD-swizzled so each XCD serves 4 value slices (3.4MB, L2-resident).
__global__ __launch_bounds__(256) void sample_kernel(
    const float* __restrict__ offt, const float* __restrict__ attnt,
    const u16* __restrict__ value, const float* __restrict__ refp,
    u16* __restrict__ samp)
{
    int bid = blockIdx.x;                       // 1664 = 8 * 208
    int lb  = (bid & 7) * 208 + (bid >> 3);     // bijective XCD swizzle
    int bh  = lb / 52;                          // 0..31 = b*8+h
    int tblk = lb - bh * 52;
    int tok = tblk * 256 + threadIdx.x;
    if (tok >= LEN_T) return;
    int b = bh >> 3, h = bh & 7;
    size_t row = (size_t)b * LEN_T + tok;

    // softmax over 16 logits (coalesced 64B read)
    const float* ap = attnt + ((size_t)h * M_TOK + row) * 16;
    float aw[16];
#pragma unroll
    for (int i = 0; i < 4; ++i) {
        float4 v = ((const float4*)ap)[i];
        aw[4*i+0] = v.x; aw[4*i+1] = v.y; aw[4*i+2] = v.z; aw[4*i+3] = v.w;
    }
    float mx = -1e30f;
#pragma unroll
    for (int i = 0; i < 16; ++i) mx = fmaxf(mx, aw[i]);
    float ssum = 0.f;
#pragma unroll
    for (int i = 0; i < 16; ++i) { aw[i] = __expf(aw[i] - mx); ssum += aw[i]; }
    float inv = 1.0f / ssum;
#pragma unroll
    for (int i = 0; i < 16; ++i) aw[i] *= inv;

    float acc[32];
#pragma unroll
    for (int d = 0; d < 32; ++d) acc[d] = 0.f;

    const float* op = offt + ((size_t)h * M_TOK + row) * 32;  // coalesced 128B read
    const float* rp = refp + row * 8;

    const int Wl[4] = {100, 50, 25, 13};
    const int Sl[4] = {0, 10000, 12500, 13125};

#pragma unroll
    for (int l = 0; l < 4; ++l) {
        const int W_ = Wl[l];
        const int H_ = Wl[l];
        const float Wf = (float)W_;
        const float invW = 1.0f / Wf;
        const u16* vb = value + ((size_t)bh * LEN_T + Sl[l]) * 32;
        float rx = rp[l*2+0], ry = rp[l*2+1];
#pragma unroll
        for (int p = 0; p < 4; ++p) {
            float dx = op[l*8 + p*2 + 0];
            float dy = op[l*8 + p*2 + 1];
            float x = fmaf(fmaf(dx, invW, rx), Wf, -0.5f);
            float y = fmaf(fmaf(dy, invW, ry), Wf, -0.5f);
            float x0f = floorf(x), y0f = floorf(y);
            int x0 = (int)x0f, y0 = (int)y0f;
            float wx = x - x0f, wy = y - y0f;
            float a = aw[l*4+p];
            float w00 = (1.f-wx)*(1.f-wy)*a;
            float w10 = wx*(1.f-wy)*a;
            float w01 = (1.f-wx)*wy*a;
            float w11 = wx*wy*a;
            corner_acc(vb, x0,   y0,   W_, H_, w00, acc);
            corner_acc(vb, x0+1, y0,   W_, H_, w10, acc);
            corner_acc(vb, x0,   y0+1, W_, H_, w01, acc);
            corner_acc(vb, x0+1, y0+1, W_, H_, w11, acc);
        }
    }
    uint32_t u[16];
#pragma unroll
    for (int i = 0; i < 16; ++i)
        u[i] = (uint32_t)f2bf(acc[2*i]) | ((uint32_t)f2bf(acc[2*i+1]) << 16);
    uint4* sp = (uint4*)(samp + row * 256 + h * 32);
#pragma unroll
    for (int i = 0; i < 4; ++i)
        sp[i] = make_uint4(u[4*i], u[4*i+1], u[4*i+2], u[4*i+3]);
}

// ---------------- LayerNorm (wave per row of 256) ------------------------------
template<int WRITE_BF16>
__global__ __launch_bounds__(256) void ln_kernel(
    const float* __restrict__ in, const float* __restrict__ g, const float* __restrict__ bb,
    u16* __restrict__ outb, float* __restrict__ outf)
{
    int row = blockIdx.x * 4 + (threadIdx.x >> 6);
    int lane = threadIdx.x & 63;
    const float4 v = *(const float4*)(in + (size_t)row * 256 + lane * 4);
    float s = v.x + v.y + v.z + v.w;
#pragma unroll
    for (int o = 1; o < 64; o <<= 1) s += __shfl_xor(s, o);
    float mu = s * (1.0f / 256.0f);
    float d0 = v.x - mu, d1 = v.y - mu, d2 = v.z - mu, d3 = v.w - mu;
    float q = d0*d0 + d1*d1 + d2*d2 + d3*d3;
#pragma unroll
    for (int o = 1; o < 64; o <<= 1) q += __shfl_xor(q, o);
    float rs = rsqrtf(q * (1.0f / 256.0f) + 1e-5f);
    float4 gv = *(const float4*)(g + lane * 4);
    float4 bv = *(const float4*)(bb + lane * 4);
    float o0 = d0 * rs * gv.x + bv.x;
    float o1 = d1 * rs * gv.y + bv.y;
    float o2 = d2 * rs * gv.z + bv.z;
    float o3 = d3 * rs * gv.w + bv.w;
    if (WRITE_BF16) {
        uint32_t u0 = (uint32_t)f2bf(o0) | ((uint32_t)f2bf(o1) << 16);
        uint32_t u1 = (uint32_t)f2bf(o2) | ((uint32_t)f2bf(o3) << 16);
        *(uint2*)(outb + (size_t)row * 256 + lane * 4) = make_uint2(u0, u1);
    } else {
        *(float4*)(outf + (size_t)row * 256 + lane * 4) = make_float4(o0, o1, o2, o3);
    }
}

// ---------------- launcher -----------------------------------------------------
extern "C" void kernel_launch(void* const* d_in, const int* in_sizes, int n_in,
                              void* d_out, int out_size, void* d_ws, size_t ws_size,
                              hipStream_t stream)
{
    const float* features = (const float*)d_in[0];
    const float* pos      = (const float*)d_in[1];
    const float* refp     = (const float*)d_in[2];
    const float* W_off  = (const float*)d_in[5];
    const float* b_off  = (const float*)d_in[6];
    const float* W_attn = (const float*)d_in[7];
    const float* b_attn = (const float*)d_in[8];
    const float* W_val  = (const float*)d_in[9];
    const float* b_val  = (const float*)d_in[10];
    const float* W_out  = (const float*)d_in[11];
    const float* b_out  = (const float*)d_in[12];
    const float* ln1_g  = (const float*)d_in[13];
    const float* ln1_b  = (const float*)d_in[14];
    const float* W1     = (const float*)d_in[15];
    const float* b1     = (const float*)d_in[16];
    const float* W2     = (const float*)d_in[17];
    const float* b2     = (const float*)d_in[18];
    const float* ln2_g  = (const float*)d_in[19];
    const float* ln2_b  = (const float*)d_in[20];
    float* out = (float*)d_out;

    char* ws = (char*)d_ws;
    size_t o = 0;
    auto alloc = [&](size_t bytes) { char* p = ws + o; o += (bytes + 255) & ~(size_t)255; return p; };
    u16* Wt_val = (u16*)alloc((size_t)256 * 256 * 2);
    u16* Wt_oa  = (u16*)alloc((size_t)384 * 256 * 2);
    u16* Wt_out = (u16*)alloc((size_t)256 * 256 * 2);
    u16* Wt1    = (u16*)alloc((size_t)1024 * 256 * 2);
    u16* Wt2    = (u16*)alloc((size_t)256 * 1024 * 2);
    u16* qb     = (u16*)alloc((size_t)M_TOK * 256 * 2);   // later reused as x_bf16
    u16* fb     = (u16*)alloc((size_t)M_TOK * 256 * 2);   // later reused as samp
    char* big   = alloc((size_t)M_TOK * 1024 * 2);        // value|off_t|attn_t, later h
    u16*   value = (u16*)big;
    float* offt  = (float*)(big + (size_t)M_TOK * 256 * 2);
    float* attnt = (float*)(big + (size_t)M_TOK * 256 * 2 + (size_t)M_TOK * 256 * 4);
    u16*   hbuf  = (u16*)big;
    u16* xb   = qb;
    u16* samp = fb;

    dim3 blk(256);
    const int mb = (M_TOK + 127) / 128;      // 416

    prep_qf<<<2048, blk, 0, stream>>>(features, pos, qb, fb, M_TOK * 256 / 4);
    wtrans_all<<<2944, blk, 0, stream>>>(W_val, W_off, W_attn, W_out, W1, W2,
                                         Wt_val, Wt_oa, Wt_out, Wt1, Wt2);

    gemm128<MODE_VAL><<<dim3(mb, 2), blk, 0, stream>>>(
        fb, Wt_val, M_TOK, 256, b_val, nullptr, nullptr, nullptr, value, nullptr);
    gemm128<MODE_OFFATTN><<<dim3(mb, 3), blk, 0, stream>>>(
        qb, Wt_oa, M_TOK, 256, b_off, b_attn, nullptr, nullptr, offt, attnt);

    sample_kernel<<<1664, blk, 0, stream>>>(offt, attnt, value, refp, samp);

    gemm128<MODE_OUT><<<dim3(mb, 2), blk, 0, stream>>>(
        samp, Wt_out, M_TOK, 256, b_out, nullptr, features, nullptr, out, nullptr);

    ln_kernel<1><<<M_TOK / 4, blk, 0, stream>>>(out, ln1_g, ln1_b, xb, nullptr);

    gemm128<MODE_FFN1><<<dim3(mb, 8), blk, 0, stream>>>(
        xb, Wt1, M_TOK, 256, b1, nullptr, nullptr, nullptr, hbuf, nullptr);
    gemm128<MODE_FFN2><<<dim3(mb, 2), blk, 0, stream>>>(
        hbuf, Wt2, M_TOK, 1024, b2, nullptr, nullptr, xb, out, nullptr);

    ln_kernel<0><<<M_TOK / 4, blk, 0, stream>>>(out, ln2_g, ln2_b, nullptr, out);
}

// Round 4
// 460.962 us; speedup vs baseline: 1.8748x; 1.2287x over previous
//
#include <hip/hip_runtime.h>
#include <stdint.h>

#define LEN_T 13294
#define M_TOK 53176   // 4 * 13294

typedef unsigned short u16;
typedef __bf16 bf16x8 __attribute__((ext_vector_type(8)));
typedef float f32x4 __attribute__((ext_vector_type(4)));
typedef uint32_t u32x4 __attribute__((ext_vector_type(4)));

__device__ __forceinline__ u16 f2bf(float f) {
    union { float f; uint32_t u; } v; v.f = f;
    uint32_t r = v.u + 0x7fffu + ((v.u >> 16) & 1u);
    return (u16)(r >> 16);
}
__device__ __forceinline__ float bf2f(u16 s) {
    union { uint32_t u; float f; } v; v.u = ((uint32_t)s) << 16;
    return v.f;
}
__device__ __forceinline__ float blo(uint32_t u) {
    union { uint32_t u; float f; } v; v.u = u << 16; return v.f;
}
__device__ __forceinline__ float bhi(uint32_t u) {
    union { uint32_t u; float f; } v; v.u = u & 0xffff0000u; return v.f;
}

__device__ __forceinline__ void gload_lds16(const u16* g, u16* l) {
    __builtin_amdgcn_global_load_lds(
        (const __attribute__((address_space(1))) uint32_t*)(g),
        (__attribute__((address_space(3))) uint32_t*)(l), 16, 0, 0);
}

// ---------------- prep: q = bf16(features+pos), f = bf16(features) -------------
__global__ __launch_bounds__(256) void prep_qf(
    const float* __restrict__ feat, const float* __restrict__ pos,
    u16* __restrict__ qb, u16* __restrict__ fb, int n4)
{
    int i = blockIdx.x * blockDim.x + threadIdx.x;
    int stride = gridDim.x * blockDim.x;
    for (; i < n4; i += stride) {
        float4 f = ((const float4*)feat)[i];
        float4 p = ((const float4*)pos)[i];
        uint32_t q0 = (uint32_t)f2bf(f.x + p.x) | ((uint32_t)f2bf(f.y + p.y) << 16);
        uint32_t q1 = (uint32_t)f2bf(f.z + p.z) | ((uint32_t)f2bf(f.w + p.w) << 16);
        uint32_t f0 = (uint32_t)f2bf(f.x) | ((uint32_t)f2bf(f.y) << 16);
        uint32_t f1 = (uint32_t)f2bf(f.z) | ((uint32_t)f2bf(f.w) << 16);
        ((uint2*)qb)[i] = make_uint2(q0, q1);
        ((uint2*)fb)[i] = make_uint2(f0, f1);
    }
}

// ---------------- all weight transposes to (N x K) bf16, one launch ------------
__global__ __launch_bounds__(256) void wtrans_all(
    const float* __restrict__ W_val, const float* __restrict__ W_off,
    const float* __restrict__ W_attn, const float* __restrict__ W_out,
    const float* __restrict__ W1, const float* __restrict__ W2,
    u16* __restrict__ Wt_val, u16* __restrict__ Wt_oa,
    u16* __restrict__ Wt_out, u16* __restrict__ Wt1, u16* __restrict__ Wt2)
{
    int gid = blockIdx.x * 256 + threadIdx.x;
    const float* W; u16* D; int K, N, off;
    if      (gid < 65536)  { W = W_val;  D = Wt_val;        K = 256;  N = 256;  off = gid; }
    else if (gid < 131072) { W = W_off;  D = Wt_oa;         K = 256;  N = 256;  off = gid - 65536; }
    else if (gid < 163840) { W = W_attn; D = Wt_oa + 65536; K = 256;  N = 128;  off = gid - 131072; }
    else if (gid < 229376) { W = W_out;  D = Wt_out;        K = 256;  N = 256;  off = gid - 163840; }
    else if (gid < 491520) { W = W1;     D = Wt1;           K = 256;  N = 1024; off = gid - 229376; }
    else if (gid < 753664) { W = W2;     D = Wt2;           K = 1024; N = 256;  off = gid - 491520; }
    else return;
    int n = off / K, k = off - n * K;
    D[off] = f2bf(W[(size_t)k * N + n]);
}

// ---------------- 128x128-tile MFMA GEMM (m97 structure) with fused epilogues --
#define MODE_VAL 0
#define MODE_OFFATTN 1
#define MODE_FFN1 3

template<int MODE>
__global__ __launch_bounds__(256, 2) void gemm128(
    const u16* __restrict__ A, const u16* __restrict__ Bt,
    int M, int K,
    const float* __restrict__ bias, const float* __restrict__ bias2,
    void* __restrict__ out0, void* __restrict__ out1)
{
    __shared__ u16 Al[128 * 64];
    __shared__ u16 Bl[128 * 64];
    const int tid = threadIdx.x;
    const int lane = tid & 63;
    const int w = tid >> 6;
    const int wr = w >> 1, wc = w & 1;     // 2x2 wave grid, 64x64 per wave
    const int m0 = blockIdx.x * 128;
    const int n0 = blockIdx.y * 128;
    const int l15 = lane & 15;
    const int kg = lane >> 4;
    const int srow = lane >> 3;            // 0..7 within 8-row chunk
    const int scol = (lane & 7) * 8;       // 16B-aligned col

    f32x4 acc[4][4];
#pragma unroll
    for (int i = 0; i < 4; ++i)
#pragma unroll
        for (int j = 0; j < 4; ++j)
            acc[i][j] = (f32x4){0.f, 0.f, 0.f, 0.f};

    const int nk = K >> 6;
    for (int kc = 0; kc < nk; ++kc) {
        __syncthreads();
#pragma unroll
        for (int j = 0; j < 4; ++j) {
            int c = w * 4 + j;             // chunk 0..15, each 1KB (8 rows x 64 elems)
            int arow = m0 + c * 8 + srow;
            arow = arow < M ? arow : M - 1;
            gload_lds16(A + (size_t)arow * K + (kc << 6) + scol, Al + c * 512);
            int brow = n0 + c * 8 + srow;  // N is always a multiple of 128
            gload_lds16(Bt + (size_t)brow * K + (kc << 6) + scol, Bl + c * 512);
        }
        __syncthreads();
#pragma unroll
        for (int ks = 0; ks < 2; ++ks) {
            bf16x8 af[4], bfr[4];
#pragma unroll
            for (int i = 0; i < 4; ++i) {
                af[i]  = *(const bf16x8*)(Al + (wr * 64 + i * 16 + l15) * 64 + ks * 32 + kg * 8);
                bfr[i] = *(const bf16x8*)(Bl + (wc * 64 + i * 16 + l15) * 64 + ks * 32 + kg * 8);
            }
#pragma unroll
            for (int mi = 0; mi < 4; ++mi)
#pragma unroll
                for (int ni = 0; ni < 4; ++ni)
                    acc[mi][ni] = __builtin_amdgcn_mfma_f32_16x16x32_bf16(
                        af[mi], bfr[ni], acc[mi][ni], 0, 0, 0);
        }
    }

    // epilogue: C/D layout col = lane&15, row = (lane>>4)*4 + reg
#pragma unroll
    for (int mi = 0; mi < 4; ++mi) {
#pragma unroll
        for (int r = 0; r < 4; ++r) {
            int row = m0 + wr * 64 + mi * 16 + kg * 4 + r;
            if (row >= M) continue;
#pragma unroll
            for (int ni = 0; ni < 4; ++ni) {
                int col = n0 + wc * 64 + ni * 16 + l15;
                float v = acc[mi][ni][r];
                if (MODE == MODE_VAL) {
                    int bI = row / LEN_T;
                    int t = row - bI * LEN_T;
                    int hh = col >> 5, d = col & 31;
                    ((u16*)out0)[((size_t)(bI * 8 + hh) * LEN_T + t) * 32 + d] =
                        f2bf(v + bias[col]);
                } else if (MODE == MODE_OFFATTN) {
                    if (col < 256) {
                        // off transposed: [h][tok][32]
                        ((float*)out0)[((size_t)(col >> 5) * M_TOK + row) * 32 + (col & 31)] =
                            v + bias[col];
                    } else {
                        int c = col - 256;
                        // attn transposed: [h][tok][16]
                        ((float*)out1)[((size_t)(c >> 4) * M_TOK + row) * 16 + (c & 15)] =
                            v + bias2[c];
                    }
                } else { // MODE_FFN1
                    float x = v + bias[col];
                    ((u16*)out0)[(size_t)row * 1024 + col] = f2bf(x > 0.f ? x : 0.f);
                }
            }
        }
    }
}

// ---------------- 64-row GEMM with fused LayerNorm epilogue --------------------
// tile 64(M) x 256(N), 4 waves each doing 64x64. N is exactly 256.
template<int KSTEPS, int OUTF32>
__global__ __launch_bounds__(256, 2) void gemm_ln(
    const u16* __restrict__ A, const u16* __restrict__ Bt,
    const float* __restrict__ bias, const u16* __restrict__ res,
    const float* __restrict__ g, const float* __restrict__ bb,
    u16* __restrict__ outb, float* __restrict__ outf, int M)
{
    __shared__ char ldsraw[66560];
    u16* Al = (u16*)ldsraw;                 // [64][64]
    u16* Bl = (u16*)(ldsraw + 8192);        // [256][64]
    float* dump = (float*)ldsraw;           // [64][260] (aliases stage bufs)
    const int tid = threadIdx.x;
    const int lane = tid & 63;
    const int w = tid >> 6;
    const int l15 = lane & 15;
    const int kg = lane >> 4;
    const int srow = lane >> 3;
    const int scol = (lane & 7) * 8;
    const int m0 = blockIdx.x * 64;
    const int K = KSTEPS * 64;

    f32x4 acc[4][4];
#pragma unroll
    for (int i = 0; i < 4; ++i)
#pragma unroll
        for (int j = 0; j < 4; ++j)
            acc[i][j] = (f32x4){0.f, 0.f, 0.f, 0.f};

    for (int kc = 0; kc < KSTEPS; ++kc) {
        __syncthreads();
#pragma unroll
        for (int j = 0; j < 2; ++j) {       // A: 8 chunks of 8 rows
            int c = w * 2 + j;
            int arow = m0 + c * 8 + srow;
            arow = arow < M ? arow : M - 1;
            gload_lds16(A + (size_t)arow * K + (kc << 6) + scol, Al + c * 512);
        }
#pragma unroll
        for (int j = 0; j < 8; ++j) {       // B: 32 chunks of 8 rows
            int c = w * 8 + j;
            int brow = c * 8 + srow;
            gload_lds16(Bt + (size_t)brow * K + (kc << 6) + scol, Bl + c * 512);
        }
        __syncthreads();
#pragma unroll
        for (int ks = 0; ks < 2; ++ks) {
            bf16x8 af[4], bfr[4];
#pragma unroll
            for (int i = 0; i < 4; ++i) {
                af[i]  = *(const bf16x8*)(Al + (i * 16 + l15) * 64 + ks * 32 + kg * 8);
                bfr[i] = *(const bf16x8*)(Bl + (w * 64 + i * 16 + l15) * 64 + ks * 32 + kg * 8);
            }
#pragma unroll
            for (int mi = 0; mi < 4; ++mi)
#pragma unroll
                for (int ni = 0; ni < 4; ++ni)
                    acc[mi][ni] = __builtin_amdgcn_mfma_f32_16x16x32_bf16(
                        af[mi], bfr[ni], acc[mi][ni], 0, 0, 0);
        }
    }

    __syncthreads();   // staging reads done before dump overwrites Al/Bl
    // dump acc + bias + residual(bf16) to LDS [64][260]
#pragma unroll
    for (int mi = 0; mi < 4; ++mi) {
#pragma unroll
        for (int r = 0; r < 4; ++r) {
            int rr = mi * 16 + kg * 4 + r;
            int gr = m0 + rr; gr = gr < M ? gr : M - 1;
#pragma unroll
            for (int ni = 0; ni < 4; ++ni) {
                int col = w * 64 + ni * 16 + l15;
                dump[rr * 260 + col] = acc[mi][ni][r] + bias[col] +
                                       bf2f(res[(size_t)gr * 256 + col]);
            }
        }
    }
    __syncthreads();

    // LayerNorm: wave w handles rows w*16 .. w*16+15
    float4 gv = *(const float4*)(g + lane * 4);
    float4 bv = *(const float4*)(bb + lane * 4);
#pragma unroll
    for (int i = 0; i < 16; ++i) {
        int rr = w * 16 + i;
        float4 x = *(const float4*)(dump + rr * 260 + lane * 4);
        float s1 = x.x + x.y + x.z + x.w;
        float s2 = x.x*x.x + x.y*x.y + x.z*x.z + x.w*x.w;
#pragma unroll
        for (int o = 1; o < 64; o <<= 1) {
            s1 += __shfl_xor(s1, o);
            s2 += __shfl_xor(s2, o);
        }
        float mu = s1 * (1.0f / 256.0f);
        float var = s2 * (1.0f / 256.0f) - mu * mu;
        float rs = rsqrtf(var + 1e-5f);
        float o0 = (x.x - mu) * rs * gv.x + bv.x;
        float o1 = (x.y - mu) * rs * gv.y + bv.y;
        float o2 = (x.z - mu) * rs * gv.z + bv.z;
        float o3 = (x.w - mu) * rs * gv.w + bv.w;
        int grow = m0 + rr;
        if (grow < M) {
            if (OUTF32) {
                *(float4*)(outf + (size_t)grow * 256 + lane * 4) =
                    make_float4(o0, o1, o2, o3);
            } else {
                uint32_t u0 = (uint32_t)f2bf(o0) | ((uint32_t)f2bf(o1) << 16);
                uint32_t u1 = (uint32_t)f2bf(o2) | ((uint32_t)f2bf(o3) << 16);
                *(uint2*)(outb + (size_t)grow * 256 + lane * 4) = make_uint2(u0, u1);
            }
        }
    }
}

// ---------------- deformable sampling: 4 threads per (tok,head) ----------------
__device__ __forceinline__ void acc8(u32x4 v, float w, float* acc) {
    acc[0] = fmaf(w, blo(v.x), acc[0]);
    acc[1] = fmaf(w, bhi(v.x), acc[1]);
    acc[2] = fmaf(w, blo(v.y), acc[2]);
    acc[3] = fmaf(w, bhi(v.y), acc[3]);
    acc[4] = fmaf(w, blo(v.z), acc[4]);
    acc[5] = fmaf(w, bhi(v.z), acc[5]);
    acc[6] = fmaf(w, blo(v.w), acc[6]);
    acc[7] = fmaf(w, bhi(v.w), acc[7]);
}

__global__ __launch_bounds__(256) void sample_kernel(
    const float* __restrict__ offt, const float* __restrict__ attnt,
    const u16* __restrict__ value, const float* __restrict__ refp,
    u16* __restrict__ samp)
{
    int bid = blockIdx.x;                        // 6656 = 8 * 832
    int lb  = (bid & 7) * 832 + (bid >> 3);      // bijective XCD swizzle
    int bh  = lb / 208;                          // 0..31 = b*8+h
    int tblk = lb - bh * 208;
    int pr  = threadIdx.x >> 2;                  // pair 0..63
    int dq  = threadIdx.x & 3;                   // dim-quarter (8 dims = 16B)
    int tok = tblk * 64 + pr;
    if (tok >= LEN_T) return;
    int b = bh >> 3, h = bh & 7;
    size_t row = (size_t)b * LEN_T + tok;

    // softmax over 16 logits (4-lane broadcast of same 64B line)
    const f32x4* ap = (const f32x4*)(attnt + ((size_t)h * M_TOK + row) * 16);
    float aw[16];
#pragma unroll
    for (int i = 0; i < 4; ++i) {
        f32x4 v = __builtin_nontemporal_load(ap + i);
        aw[4*i+0] = v.x; aw[4*i+1] = v.y; aw[4*i+2] = v.z; aw[4*i+3] = v.w;
    }
    float mx = -1e30f;
#pragma unroll
    for (int i = 0; i < 16; ++i) mx = fmaxf(mx, aw[i]);
    float ssum = 0.f;
#pragma unroll
    for (int i = 0; i < 16; ++i) { aw[i] = __expf(aw[i] - mx); ssum += aw[i]; }
    float inv = 1.0f / ssum;
#pragma unroll
    for (int i = 0; i < 16; ++i) aw[i] *= inv;

    const f32x4* rp4 = (const f32x4*)(refp + row * 8);
    f32x4 r01 = __builtin_nontemporal_load(rp4);
    f32x4 r23 = __builtin_nontemporal_load(rp4 + 1);
    float rxy[8] = {r01.x, r01.y, r01.z, r01.w, r23.x, r23.y, r23.z, r23.w};

    float acc[8];
#pragma unroll
    for (int d = 0; d < 8; ++d) acc[d] = 0.f;

    const f32x4* op4 = (const f32x4*)(offt + ((size_t)h * M_TOK + row) * 32);

    const int Wl[4] = {100, 50, 25, 13};
    const int Sl[4] = {0, 10000, 12500, 13125};

#pragma unroll
    for (int l = 0; l < 4; ++l) {
        const int W_ = Wl[l];
        const float Wf = (float)W_;
        const float invW = 1.0f / Wf;
        const u16* vb = value + ((size_t)bh * LEN_T + Sl[l]) * 32 + dq * 8;
        float rx = rxy[l*2+0], ry = rxy[l*2+1];
        f32x4 o0 = __builtin_nontemporal_load(op4 + l*2);      // p0: xy, p1: zw
        f32x4 o1 = __builtin_nontemporal_load(op4 + l*2 + 1);  // p2: xy, p3: zw
        float dxs[4] = {o0.x, o0.z, o1.x, o1.z};
        float dys[4] = {o0.y, o0.w, o1.y, o1.w};
#pragma unroll
        for (int p = 0; p < 4; ++p) {
            float x = fmaf(fmaf(dxs[p], invW, rx), Wf, -0.5f);
            float y = fmaf(fmaf(dys[p], invW, ry), Wf, -0.5f);
            float x0f = floorf(x), y0f = floorf(y);
            int x0 = (int)x0f, y0 = (int)y0f;
            int x1 = x0 + 1, y1 = y0 + 1;
            float wx = x - x0f, wy = y - y0f;
            // validity masks (reference: clip index, zero weight)
            float vx0 = ((unsigned)x0 < (unsigned)W_) ? 1.f : 0.f;
            float vx1 = ((unsigned)x1 < (unsigned)W_) ? 1.f : 0.f;
            float vy0 = ((unsigned)y0 < (unsigned)W_) ? 1.f : 0.f;
            float vy1 = ((unsigned)y1 < (unsigned)W_) ? 1.f : 0.f;
            int cx0 = min(max(x0, 0), W_ - 1);
            int cx1 = min(max(x1, 0), W_ - 1);
            int cy0 = min(max(y0, 0), W_ - 1);
            int cy1 = min(max(y1, 0), W_ - 1);
            float a = aw[l*4 + p];
            float w00 = (1.f - wx) * (1.f - wy) * a * vx0 * vy0;
            float w10 = wx * (1.f - wy) * a * vx1 * vy0;
            float w01 = (1.f - wx) * wy * a * vx0 * vy1;
            float w11 = wx * wy * a * vx1 * vy1;
            u32x4 v00 = *(const u32x4*)(vb + (size_t)(cy0 * W_ + cx0) * 32);
            u32x4 v10 = *(const u32x4*)(vb + (size_t)(cy0 * W_ + cx1) * 32);
            u32x4 v01 = *(const u32x4*)(vb + (size_t)(cy1 * W_ + cx0) * 32);
            u32x4 v11 = *(const u32x4*)(vb + (size_t)(cy1 * W_ + cx1) * 32);
            acc8(v00, w00, acc);
            acc8(v10, w10, acc);
            acc8(v01, w01, acc);
            acc8(v11, w11, acc);
        }
    }
    u32x4 uo;
    uo.x = (uint32_t)f2bf(acc[0]) | ((uint32_t)f2bf(acc[1]) << 16);
    uo.y = (uint32_t)f2bf(acc[2]) | ((uint32_t)f2bf(acc[3]) << 16);
    uo.z = (uint32_t)f2bf(acc[4]) | ((uint32_t)f2bf(acc[5]) << 16);
    uo.w = (uint32_t)f2bf(acc[6]) | ((uint32_t)f2bf(acc[7]) << 16);
    __builtin_nontemporal_store(uo, (u32x4*)(samp + row * 256 + h * 32 + dq * 8));
}

// ---------------- launcher -----------------------------------------------------
extern "C" void kernel_launch(void* const* d_in, const int* in_sizes, int n_in,
                              void* d_out, int out_size, void* d_ws, size_t ws_size,
                              hipStream_t stream)
{
    const float* features = (const float*)d_in[0];
    const float* pos      = (const float*)d_in[1];
    const float* refp     = (const float*)d_in[2];
    const float* W_off  = (const float*)d_in[5];
    const float* b_off  = (const float*)d_in[6];
    const float* W_attn = (const float*)d_in[7];
    const float* b_attn = (const float*)d_in[8];
    const float* W_val  = (const float*)d_in[9];
    const float* b_val  = (const float*)d_in[10];
    const float* W_out  = (const float*)d_in[11];
    const float* b_out  = (const float*)d_in[12];
    const float* ln1_g  = (const float*)d_in[13];
    const float* ln1_b  = (const float*)d_in[14];
    const float* W1     = (const float*)d_in[15];
    const float* b1     = (const float*)d_in[16];
    const float* W2     = (const float*)d_in[17];
    const float* b2     = (const float*)d_in[18];
    const float* ln2_g  = (const float*)d_in[19];
    const float* ln2_b  = (const float*)d_in[20];
    float* out = (float*)d_out;

    char* ws = (char*)d_ws;
    size_t o = 0;
    auto alloc = [&](size_t bytes) { char* p = ws + o; o += (bytes + 255) & ~(size_t)255; return p; };
    u16* Wt_val = (u16*)alloc((size_t)256 * 256 * 2);
    u16* Wt_oa  = (u16*)alloc((size_t)384 * 256 * 2);
    u16* Wt_out = (u16*)alloc((size_t)256 * 256 * 2);
    u16* Wt1    = (u16*)alloc((size_t)1024 * 256 * 2);
    u16* Wt2    = (u16*)alloc((size_t)256 * 1024 * 2);
    u16* qb     = (u16*)alloc((size_t)M_TOK * 256 * 2);   // q -> samp -> x (bf16)
    u16* fb     = (u16*)alloc((size_t)M_TOK * 256 * 2);   // features bf16
    char* big   = alloc((size_t)M_TOK * 1024 * 2);        // value|off_t|attn_t, later h
    u16*   value = (u16*)big;
    float* offt  = (float*)(big + (size_t)M_TOK * 256 * 2);
    float* attnt = (float*)(big + (size_t)M_TOK * 256 * 2 + (size_t)M_TOK * 256 * 4);
    u16*   hbuf  = (u16*)big;
    u16* samp = qb;   // qb dead after OFFATTN gemm
    u16* xb   = qb;   // gemm_ln writes each block's rows after reading them

    dim3 blk(256);
    const int mb  = (M_TOK + 127) / 128;     // 416
    const int mb64 = (M_TOK + 63) / 64;      // 831

    prep_qf<<<2048, blk, 0, stream>>>(features, pos, qb, fb, M_TOK * 256 / 4);
    wtrans_all<<<2944, blk, 0, stream>>>(W_val, W_off, W_attn, W_out, W1, W2,
                                         Wt_val, Wt_oa, Wt_out, Wt1, Wt2);

    gemm128<MODE_VAL><<<dim3(mb, 2), blk, 0, stream>>>(
        fb, Wt_val, M_TOK, 256, b_val, nullptr, value, nullptr);
    gemm128<MODE_OFFATTN><<<dim3(mb, 3), blk, 0, stream>>>(
        qb, Wt_oa, M_TOK, 256, b_off, b_attn, offt, attnt);

    sample_kernel<<<6656, blk, 0, stream>>>(offt, attnt, value, refp, samp);

    // W_out GEMM + residual(features bf16) + LN1 -> xb (bf16)
    gemm_ln<4, 0><<<mb64, blk, 0, stream>>>(
        samp, Wt_out, b_out, fb, ln1_g, ln1_b, xb, nullptr, M_TOK);

    gemm128<MODE_FFN1><<<dim3(mb, 8), blk, 0, stream>>>(
        xb, Wt1, M_TOK, 256, b1, nullptr, hbuf, nullptr);

    // FFN2 GEMM + residual(xb bf16) + LN2 -> out (f32)
    gemm_ln<16, 1><<<mb64, blk, 0, stream>>>(
        hbuf, Wt2, b2, xb, ln2_g, ln2_b, nullptr, out, M_TOK);
}

// Round 5
// 375.360 us; speedup vs baseline: 2.3024x; 1.2281x over previous
//
#include <hip/hip_runtime.h>
#include <stdint.h>

#define LEN_T 13294
#define M_TOK 53176   // 4 * 13294

typedef unsigned short u16;
typedef __bf16 bf16x8 __attribute__((ext_vector_type(8)));
typedef float f32x4 __attribute__((ext_vector_type(4)));
typedef uint32_t u32x4 __attribute__((ext_vector_type(4)));

__device__ __forceinline__ u16 f2bf(float f) {
    union { float f; uint32_t u; } v; v.f = f;
    uint32_t r = v.u + 0x7fffu + ((v.u >> 16) & 1u);
    return (u16)(r >> 16);
}
__device__ __forceinline__ float bf2f(u16 s) {
    union { uint32_t u; float f; } v; v.u = ((uint32_t)s) << 16;
    return v.f;
}
__device__ __forceinline__ u16 f2h(float f) {
    union { _Float16 h; u16 u; } c; c.h = (_Float16)f; return c.u;
}
__device__ __forceinline__ float hlo(uint32_t u) {
    union { uint32_t u; _Float16 h[2]; } v; v.u = u; return (float)v.h[0];
}
__device__ __forceinline__ float hhi(uint32_t u) {
    union { uint32_t u; _Float16 h[2]; } v; v.u = u; return (float)v.h[1];
}

__device__ __forceinline__ void gload_lds16(const u16* g, u16* l) {
    __builtin_amdgcn_global_load_lds(
        (const __attribute__((address_space(1))) uint32_t*)(g),
        (__attribute__((address_space(3))) uint32_t*)(l), 16, 0, 0);
}

// ---------------- prep: q = bf16(features+pos), f = bf16(features) -------------
__global__ __launch_bounds__(256) void prep_qf(
    const float* __restrict__ feat, const float* __restrict__ pos,
    u16* __restrict__ qb, u16* __restrict__ fb, int n4)
{
    int i = blockIdx.x * blockDim.x + threadIdx.x;
    int stride = gridDim.x * blockDim.x;
    for (; i < n4; i += stride) {
        float4 f = ((const float4*)feat)[i];
        float4 p = ((const float4*)pos)[i];
        uint32_t q0 = (uint32_t)f2bf(f.x + p.x) | ((uint32_t)f2bf(f.y + p.y) << 16);
        uint32_t q1 = (uint32_t)f2bf(f.z + p.z) | ((uint32_t)f2bf(f.w + p.w) << 16);
        uint32_t f0 = (uint32_t)f2bf(f.x) | ((uint32_t)f2bf(f.y) << 16);
        uint32_t f1 = (uint32_t)f2bf(f.z) | ((uint32_t)f2bf(f.w) << 16);
        ((uint2*)qb)[i] = make_uint2(q0, q1);
        ((uint2*)fb)[i] = make_uint2(f0, f1);
    }
}

// ---------------- weight prep (one launch) -------------------------------------
// Wt_val/Wt_oa/Wt_out: row-major (N x K) bf16 transposes.
// W1f/W2f: MFMA-fragment-order bf16 so B-operands load coalesced from global.
__global__ __launch_bounds__(256) void wtrans_all(
    const float* __restrict__ W_val, const float* __restrict__ W_off,
    const float* __restrict__ W_attn, const float* __restrict__ W_out,
    const float* __restrict__ W1, const float* __restrict__ W2,
    u16* __restrict__ Wt_val, u16* __restrict__ Wt_oa,
    u16* __restrict__ Wt_out, u16* __restrict__ W1f, u16* __restrict__ W2f)
{
    int gid = blockIdx.x * 256 + threadIdx.x;
    if (gid < 229376) {
        const float* W; u16* D; int K, N, off;
        if      (gid < 65536)  { W = W_val;  D = Wt_val;        K = 256; N = 256; off = gid; }
        else if (gid < 131072) { W = W_off;  D = Wt_oa;         K = 256; N = 256; off = gid - 65536; }
        else if (gid < 163840) { W = W_attn; D = Wt_oa + 65536; K = 256; N = 128; off = gid - 131072; }
        else                   { W = W_out;  D = Wt_out;        K = 256; N = 256; off = gid - 163840; }
        int n = off / K, k = off - n * K;
        D[off] = f2bf(W[(size_t)k * N + n]);
    } else if (gid < 491520) {
        // W1f[((c*2+ni)*8+ks)*512 + lane*8 + e] = W1[k][col]
        // col = c*32+ni*16+(lane&15), k = ks*32+(lane>>4)*8+e
        int off = gid - 229376;
        int e = off & 7, lane = (off >> 3) & 63;
        int r = off >> 9;
        int ks = r & 7, ni = (r >> 3) & 1, c = r >> 4;
        int col = c * 32 + ni * 16 + (lane & 15);
        int k = ks * 32 + (lane >> 4) * 8 + e;
        W1f[off] = f2bf(W1[(size_t)k * 1024 + col]);
    } else if (gid < 753664) {
        // W2f[r*512 + lane*8 + e] = W2[k][col]; r = hcks*16 + cn
        // col = cn*16+(lane&15), k = hcks*32+(lane>>4)*8+e
        int off = gid - 491520;
        int e = off & 7, lane = (off >> 3) & 63;
        int r = off >> 9;
        int col = (r & 15) * 16 + (lane & 15);
        int k = (r >> 4) * 32 + (lane >> 4) * 8 + e;
        W2f[off] = f2bf(W2[(size_t)k * 256 + col]);
    }
}

// ---------------- 128x128-tile MFMA GEMM with fused epilogues ------------------
#define MODE_VAL 0
#define MODE_OFFATTN 1

template<int MODE>
__global__ __launch_bounds__(256, 2) void gemm128(
    const u16* __restrict__ A, const u16* __restrict__ Bt,
    int M, int K,
    const float* __restrict__ bias, const float* __restrict__ bias2,
    void* __restrict__ out0, void* __restrict__ out1)
{
    __shared__ u16 Al[128 * 64];
    __shared__ u16 Bl[128 * 64];
    const int tid = threadIdx.x;
    const int lane = tid & 63;
    const int w = tid >> 6;
    const int wr = w >> 1, wc = w & 1;
    const int m0 = blockIdx.x * 128;
    const int n0 = blockIdx.y * 128;
    const int l15 = lane & 15;
    const int kg = lane >> 4;
    const int srow = lane >> 3;
    const int scol = (lane & 7) * 8;

    f32x4 acc[4][4];
#pragma unroll
    for (int i = 0; i < 4; ++i)
#pragma unroll
        for (int j = 0; j < 4; ++j)
            acc[i][j] = (f32x4){0.f, 0.f, 0.f, 0.f};

    const int nk = K >> 6;
    for (int kc = 0; kc < nk; ++kc) {
        __syncthreads();
#pragma unroll
        for (int j = 0; j < 4; ++j) {
            int c = w * 4 + j;
            int arow = m0 + c * 8 + srow;
            arow = arow < M ? arow : M - 1;
            gload_lds16(A + (size_t)arow * K + (kc << 6) + scol, Al + c * 512);
            int brow = n0 + c * 8 + srow;
            gload_lds16(Bt + (size_t)brow * K + (kc << 6) + scol, Bl + c * 512);
        }
        __syncthreads();
#pragma unroll
        for (int ks = 0; ks < 2; ++ks) {
            bf16x8 af[4], bfr[4];
#pragma unroll
            for (int i = 0; i < 4; ++i) {
                af[i]  = *(const bf16x8*)(Al + (wr * 64 + i * 16 + l15) * 64 + ks * 32 + kg * 8);
                bfr[i] = *(const bf16x8*)(Bl + (wc * 64 + i * 16 + l15) * 64 + ks * 32 + kg * 8);
            }
#pragma unroll
            for (int mi = 0; mi < 4; ++mi)
#pragma unroll
                for (int ni = 0; ni < 4; ++ni)
                    acc[mi][ni] = __builtin_amdgcn_mfma_f32_16x16x32_bf16(
                        af[mi], bfr[ni], acc[mi][ni], 0, 0, 0);
        }
    }

#pragma unroll
    for (int mi = 0; mi < 4; ++mi) {
#pragma unroll
        for (int r = 0; r < 4; ++r) {
            int row = m0 + wr * 64 + mi * 16 + kg * 4 + r;
            if (row >= M) continue;
#pragma unroll
            for (int ni = 0; ni < 4; ++ni) {
                int col = n0 + wc * 64 + ni * 16 + l15;
                float v = acc[mi][ni][r];
                if (MODE == MODE_VAL) {
                    int bI = row / LEN_T;
                    int t = row - bI * LEN_T;
                    int hh = col >> 5, d = col & 31;
                    ((u16*)out0)[((size_t)(bI * 8 + hh) * LEN_T + t) * 32 + d] =
                        f2h(v + bias[col]);           // value stored as f16
                } else { // MODE_OFFATTN
                    if (col < 256) {
                        ((float*)out0)[((size_t)(col >> 5) * M_TOK + row) * 32 + (col & 31)] =
                            v + bias[col];
                    } else {
                        int c = col - 256;
                        ((float*)out1)[((size_t)(c >> 4) * M_TOK + row) * 16 + (c & 15)] =
                            v + bias2[c];
                    }
                }
            }
        }
    }
}

// ---------------- 64-row GEMM with fused LayerNorm epilogue (W_out + LN1) ------
template<int KSTEPS, int OUTF32>
__global__ __launch_bounds__(256, 2) void gemm_ln(
    const u16* __restrict__ A, const u16* __restrict__ Bt,
    const float* __restrict__ bias, const u16* __restrict__ res,
    const float* __restrict__ g, const float* __restrict__ bb,
    u16* __restrict__ outb, float* __restrict__ outf, int M)
{
    __shared__ char ldsraw[66560];
    u16* Al = (u16*)ldsraw;                 // [64][64]
    u16* Bl = (u16*)(ldsraw + 8192);        // [256][64]
    float* dump = (float*)ldsraw;           // [64][260]
    const int tid = threadIdx.x;
    const int lane = tid & 63;
    const int w = tid >> 6;
    const int l15 = lane & 15;
    const int kg = lane >> 4;
    const int srow = lane >> 3;
    const int scol = (lane & 7) * 8;
    const int m0 = blockIdx.x * 64;
    const int K = KSTEPS * 64;

    f32x4 acc[4][4];
#pragma unroll
    for (int i = 0; i < 4; ++i)
#pragma unroll
        for (int j = 0; j < 4; ++j)
            acc[i][j] = (f32x4){0.f, 0.f, 0.f, 0.f};

    for (int kc = 0; kc < KSTEPS; ++kc) {
        __syncthreads();
#pragma unroll
        for (int j = 0; j < 2; ++j) {
            int c = w * 2 + j;
            int arow = m0 + c * 8 + srow;
            arow = arow < M ? arow : M - 1;
            gload_lds16(A + (size_t)arow * K + (kc << 6) + scol, Al + c * 512);
        }
#pragma unroll
        for (int j = 0; j < 8; ++j) {
            int c = w * 8 + j;
            int brow = c * 8 + srow;
            gload_lds16(Bt + (size_t)brow * K + (kc << 6) + scol, Bl + c * 512);
        }
        __syncthreads();
#pragma unroll
        for (int ks = 0; ks < 2; ++ks) {
            bf16x8 af[4], bfr[4];
#pragma unroll
            for (int i = 0; i < 4; ++i) {
                af[i]  = *(const bf16x8*)(Al + (i * 16 + l15) * 64 + ks * 32 + kg * 8);
                bfr[i] = *(const bf16x8*)(Bl + (w * 64 + i * 16 + l15) * 64 + ks * 32 + kg * 8);
            }
#pragma unroll
            for (int mi = 0; mi < 4; ++mi)
#pragma unroll
                for (int ni = 0; ni < 4; ++ni)
                    acc[mi][ni] = __builtin_amdgcn_mfma_f32_16x16x32_bf16(
                        af[mi], bfr[ni], acc[mi][ni], 0, 0, 0);
        }
    }

    __syncthreads();
#pragma unroll
    for (int mi = 0; mi < 4; ++mi) {
#pragma unroll
        for (int r = 0; r < 4; ++r) {
            int rr = mi * 16 + kg * 4 + r;
            int gr = m0 + rr; gr = gr < M ? gr : M - 1;
#pragma unroll
            for (int ni = 0; ni < 4; ++ni) {
                int col = w * 64 + ni * 16 + l15;
                dump[rr * 260 + col] = acc[mi][ni][r] + bias[col] +
                                       bf2f(res[(size_t)gr * 256 + col]);
            }
        }
    }
    __syncthreads();

    float4 gv = *(const float4*)(g + lane * 4);
    float4 bv = *(const float4*)(bb + lane * 4);
#pragma unroll
    for (int i = 0; i < 16; ++i) {
        int rr = w * 16 + i;
        float4 x = *(const float4*)(dump + rr * 260 + lane * 4);
        float s1 = x.x + x.y + x.z + x.w;
        float s2 = x.x*x.x + x.y*x.y + x.z*x.z + x.w*x.w;
#pragma unroll
        for (int o = 1; o < 64; o <<= 1) {
            s1 += __shfl_xor(s1, o);
            s2 += __shfl_xor(s2, o);
        }
        float mu = s1 * (1.0f / 256.0f);
        float var = s2 * (1.0f / 256.0f) - mu * mu;
        float rs = rsqrtf(var + 1e-5f);
        float o0 = (x.x - mu) * rs * gv.x + bv.x;
        float o1 = (x.y - mu) * rs * gv.y + bv.y;
        float o2 = (x.z - mu) * rs * gv.z + bv.z;
        float o3 = (x.w - mu) * rs * gv.w + bv.w;
        int grow = m0 + rr;
        if (grow < M) {
            if (OUTF32) {
                *(float4*)(outf + (size_t)grow * 256 + lane * 4) =
                    make_float4(o0, o1, o2, o3);
            } else {
                uint32_t u0 = (uint32_t)f2bf(o0) | ((uint32_t)f2bf(o1) << 16);
                uint32_t u1 = (uint32_t)f2bf(o2) | ((uint32_t)f2bf(o3) << 16);
                *(uint2*)(outb + (size_t)grow * 256 + lane * 4) = make_uint2(u0, u1);
            }
        }
    }
}

// ---------------- fused FFN: x@W1+b1 -> relu -> @W2+b2 -> +x -> LN2 -> out -----
// Block = 64 rows. A staged once in LDS (padded). W1f/W2f fragment-order from L2.
// h-tile (64x128 per chunk) lives in LDS only.
__global__ __launch_bounds__(256, 2) void ffn_fused(
    const u16* __restrict__ A, const u16* __restrict__ W1f, const u16* __restrict__ W2f,
    const float* __restrict__ b1, const float* __restrict__ b2,
    const float* __restrict__ g, const float* __restrict__ bb,
    float* __restrict__ outf, int M)
{
    __shared__ char lds[66560];
    u16* Axl = (u16*)lds;                 // [64][264] bf16
    u16* ht  = (u16*)(lds + 33792);       // [64][136] bf16
    float* dump = (float*)lds;            // [64][260] f32 (aliases, used at end)
    const int tid = threadIdx.x;
    const int lane = tid & 63;
    const int w = tid >> 6;
    const int l15 = lane & 15;
    const int kg = lane >> 4;
    const int m0 = blockIdx.x * 64;

    // stage A (64 x 256) into padded LDS via registers (pad breaks gload_lds)
#pragma unroll
    for (int i = 0; i < 8; ++i) {
        int linear = i * 256 + tid;
        int row = linear >> 5;
        int gcol = (linear & 31) * 8;
        int grow = m0 + row; grow = grow < M ? grow : M - 1;
        uint4 v = *(const uint4*)(A + (size_t)grow * 256 + gcol);
        *(uint4*)(Axl + row * 264 + gcol) = v;
    }
    __syncthreads();

    f32x4 acc[4][4];
#pragma unroll
    for (int i = 0; i < 4; ++i)
#pragma unroll
        for (int j = 0; j < 4; ++j)
            acc[i][j] = (f32x4){0.f, 0.f, 0.f, 0.f};

    for (int hc = 0; hc < 8; ++hc) {
        // ---- FFN1: htile[64][128] = relu(x @ W1[:, hc*128:+128] + b1) ----
        f32x4 acc2[4][2];
#pragma unroll
        for (int i = 0; i < 4; ++i) {
            acc2[i][0] = (f32x4){0.f, 0.f, 0.f, 0.f};
            acc2[i][1] = (f32x4){0.f, 0.f, 0.f, 0.f};
        }
#pragma unroll
        for (int ks = 0; ks < 8; ++ks) {
            bf16x8 af[4], bw[2];
#pragma unroll
            for (int ni = 0; ni < 2; ++ni)
                bw[ni] = *(const bf16x8*)(W1f +
                    ((size_t)((((hc * 4 + w) * 2 + ni) * 8 + ks)) << 9) + lane * 8);
#pragma unroll
            for (int mi = 0; mi < 4; ++mi)
                af[mi] = *(const bf16x8*)(Axl + (mi * 16 + l15) * 264 + ks * 32 + kg * 8);
#pragma unroll
            for (int mi = 0; mi < 4; ++mi)
#pragma unroll
                for (int ni = 0; ni < 2; ++ni)
                    acc2[mi][ni] = __builtin_amdgcn_mfma_f32_16x16x32_bf16(
                        af[mi], bw[ni], acc2[mi][ni], 0, 0, 0);
        }
        __syncthreads();   // prev iteration's htile reads are done
#pragma unroll
        for (int mi = 0; mi < 4; ++mi) {
#pragma unroll
            for (int ni = 0; ni < 2; ++ni) {
#pragma unroll
                for (int r = 0; r < 4; ++r) {
                    int rr = mi * 16 + kg * 4 + r;
                    int cl = w * 32 + ni * 16 + l15;
                    float hv = acc2[mi][ni][r] + b1[hc * 128 + cl];
                    ht[rr * 136 + cl] = f2bf(hv > 0.f ? hv : 0.f);
                }
            }
        }
        __syncthreads();   // htile ready
        // ---- FFN2 partial: acc += htile @ W2[hc*128:+128, :] ----
#pragma unroll
        for (int ks2 = 0; ks2 < 4; ++ks2) {
            bf16x8 ah[4], bw2[4];
#pragma unroll
            for (int ni = 0; ni < 4; ++ni)
                bw2[ni] = *(const bf16x8*)(W2f +
                    ((size_t)(((hc * 4 + ks2) * 16 + w * 4 + ni)) << 9) + lane * 8);
#pragma unroll
            for (int mi = 0; mi < 4; ++mi)
                ah[mi] = *(const bf16x8*)(ht + (mi * 16 + l15) * 136 + ks2 * 32 + kg * 8);
#pragma unroll
            for (int mi = 0; mi < 4; ++mi)
#pragma unroll
                for (int ni = 0; ni < 4; ++ni)
                    acc[mi][ni] = __builtin_amdgcn_mfma_f32_16x16x32_bf16(
                        ah[mi], bw2[ni], acc[mi][ni], 0, 0, 0);
        }
    }

    __syncthreads();   // all htile reads done before dump overwrites LDS
#pragma unroll
    for (int mi = 0; mi < 4; ++mi) {
#pragma unroll
        for (int r = 0; r < 4; ++r) {
            int rr = mi * 16 + kg * 4 + r;
            int gr = m0 + rr; gr = gr < M ? gr : M - 1;
#pragma unroll
            for (int ni = 0; ni < 4; ++ni) {
                int col = w * 64 + ni * 16 + l15;
                dump[rr * 260 + col] = acc[mi][ni][r] + b2[col] +
                                       bf2f(A[(size_t)gr * 256 + col]);   // residual = x
            }
        }
    }
    __syncthreads();

    float4 gv = *(const float4*)(g + lane * 4);
    float4 bv = *(const float4*)(bb + lane * 4);
#pragma unroll
    for (int i = 0; i < 16; ++i) {
        int rr = w * 16 + i;
        float4 x = *(const float4*)(dump + rr * 260 + lane * 4);
        float s1 = x.x + x.y + x.z + x.w;
        float s2 = x.x*x.x + x.y*x.y + x.z*x.z + x.w*x.w;
#pragma unroll
        for (int o = 1; o < 64; o <<= 1) {
            s1 += __shfl_xor(s1, o);
            s2 += __shfl_xor(s2, o);
        }
        float mu = s1 * (1.0f / 256.0f);
        float var = s2 * (1.0f / 256.0f) - mu * mu;
        float rs = rsqrtf(var + 1e-5f);
        float o0 = (x.x - mu) * rs * gv.x + bv.x;
        float o1 = (x.y - mu) * rs * gv.y + bv.y;
        float o2 = (x.z - mu) * rs * gv.z + bv.z;
        float o3 = (x.w - mu) * rs * gv.w + bv.w;
        int grow = m0 + rr;
        if (grow < M) {
            *(float4*)(outf + (size_t)grow * 256 + lane * 4) =
                make_float4(o0, o1, o2, o3);
        }
    }
}

// ---------------- deformable sampling: 4 threads per (tok,head), f16 value -----
__device__ __forceinline__ void acc8h(u32x4 v, float w, float* acc) {
    acc[0] = fmaf(hlo(v.x), w, acc[0]);
    acc[1] = fmaf(hhi(v.x), w, acc[1]);
    acc[2] = fmaf(hlo(v.y), w, acc[2]);
    acc[3] = fmaf(hhi(v.y), w, acc[3]);
    acc[4] = fmaf(hlo(v.z), w, acc[4]);
    acc[5] = fmaf(hhi(v.z), w, acc[5]);
    acc[6] = fmaf(hlo(v.w), w, acc[6]);
    acc[7] = fmaf(hhi(v.w), w, acc[7]);
}

__global__ __launch_bounds__(256, 4) void sample_kernel(
    const float* __restrict__ offt, const float* __restrict__ attnt,
    const u16* __restrict__ value, const float* __restrict__ refp,
    u16* __restrict__ samp)
{
    int bid = blockIdx.x;                        // 6656 = 8 * 832
    int lb  = (bid & 7) * 832 + (bid >> 3);      // bijective XCD swizzle
    int bh  = lb / 208;                          // 0..31 = b*8+h
    int tblk = lb - bh * 208;
    int pr  = threadIdx.x >> 2;
    int dq  = threadIdx.x & 3;
    int tok = tblk * 64 + pr;
    if (tok >= LEN_T) return;
    int b = bh >> 3, h = bh & 7;
    size_t row = (size_t)b * LEN_T + tok;

    const f32x4* ap = (const f32x4*)(attnt + ((size_t)h * M_TOK + row) * 16);
    float aw[16];
#pragma unroll
    for (int i = 0; i < 4; ++i) {
        f32x4 v = __builtin_nontemporal_load(ap + i);
        aw[4*i+0] = v.x; aw[4*i+1] = v.y; aw[4*i+2] = v.z; aw[4*i+3] = v.w;
    }
    float mx = -1e30f;
#pragma unroll
    for (int i = 0; i < 16; ++i) mx = fmaxf(mx, aw[i]);
    float ssum = 0.f;
#pragma unroll
    for (int i = 0; i < 16; ++i) { aw[i] = __expf(aw[i] - mx); ssum += aw[i]; }
    float inv = 1.0f / ssum;
#pragma unroll
    for (int i = 0; i < 16; ++i) aw[i] *= inv;

    const f32x4* rp4 = (const f32x4*)(refp + row * 8);
    f32x4 r01 = __builtin_nontemporal_load(rp4);
    f32x4 r23 = __builtin_nontemporal_load(rp4 + 1);
    float rxy[8] = {r01.x, r01.y, r01.z, r01.w, r23.x, r23.y, r23.z, r23.w};

    float acc[8];
#pragma unroll
    for (int d = 0; d < 8; ++d) acc[d] = 0.f;

    const f32x4* op4 = (const f32x4*)(offt + ((size_t)h * M_TOK + row) * 32);

    const int Wl[4] = {100, 50, 25, 13};
    const int Sl[4] = {0, 10000, 12500, 13125};

#pragma unroll
    for (int l = 0; l < 4; ++l) {
        const int W_ = Wl[l];
        const float Wf = (float)W_;
        const float invW = 1.0f / Wf;
        const u16* vb = value + ((size_t)bh * LEN_T + Sl[l]) * 32 + dq * 8;
        float rx = rxy[l*2+0], ry = rxy[l*2+1];
        f32x4 o0 = __builtin_nontemporal_load(op4 + l*2);
        f32x4 o1 = __builtin_nontemporal_load(op4 + l*2 + 1);
        float dxs[4] = {o0.x, o0.z, o1.x, o1.z};
        float dys[4] = {o0.y, o0.w, o1.y, o1.w};
        float wts[16];
        int   offs[16];
#pragma unroll
        for (int p = 0; p < 4; ++p) {
            float x = fmaf(fmaf(dxs[p], invW, rx), Wf, -0.5f);
            float y = fmaf(fmaf(dys[p], invW, ry), Wf, -0.5f);
            float x0f = floorf(x), y0f = floorf(y);
            int x0 = (int)x0f, y0 = (int)y0f;
            int x1 = x0 + 1, y1 = y0 + 1;
            float wx = x - x0f, wy = y - y0f;
            float vx0 = ((unsigned)x0 < (unsigned)W_) ? 1.f : 0.f;
            float vx1 = ((unsigned)x1 < (unsigned)W_) ? 1.f : 0.f;
            float vy0 = ((unsigned)y0 < (unsigned)W_) ? 1.f : 0.f;
            float vy1 = ((unsigned)y1 < (unsigned)W_) ? 1.f : 0.f;
            int cx0 = min(max(x0, 0), W_ - 1);
            int cx1 = min(max(x1, 0), W_ - 1);
            int cy0 = min(max(y0, 0), W_ - 1);
            int cy1 = min(max(y1, 0), W_ - 1);
            float a = aw[l*4 + p];
            wts[p*4+0] = (1.f - wx) * (1.f - wy) * a * vx0 * vy0;
            wts[p*4+1] = wx * (1.f - wy) * a * vx1 * vy0;
            wts[p*4+2] = (1.f - wx) * wy * a * vx0 * vy1;
            wts[p*4+3] = wx * wy * a * vx1 * vy1;
            offs[p*4+0] = (cy0 * W_ + cx0) * 32;
            offs[p*4+1] = (cy0 * W_ + cx1) * 32;
            offs[p*4+2] = (cy1 * W_ + cx0) * 32;
            offs[p*4+3] = (cy1 * W_ + cx1) * 32;
        }
        u32x4 vv[16];
#pragma unroll
        for (int i = 0; i < 16; ++i)
            vv[i] = *(const u32x4*)(vb + offs[i]);
#pragma unroll
        for (int i = 0; i < 16; ++i)
            acc8h(vv[i], wts[i], acc);
    }
    u32x4 uo;
    uo.x = (uint32_t)f2bf(acc[0]) | ((uint32_t)f2bf(acc[1]) << 16);
    uo.y = (uint32_t)f2bf(acc[2]) | ((uint32_t)f2bf(acc[3]) << 16);
    uo.z = (uint32_t)f2bf(acc[4]) | ((uint32_t)f2bf(acc[5]) << 16);
    uo.w = (uint32_t)f2bf(acc[6]) | ((uint32_t)f2bf(acc[7]) << 16);
    __builtin_nontemporal_store(uo, (u32x4*)(samp + row * 256 + h * 32 + dq * 8));
}

// ---------------- launcher -----------------------------------------------------
extern "C" void kernel_launch(void* const* d_in, const int* in_sizes, int n_in,
                              void* d_out, int out_size, void* d_ws, size_t ws_size,
                              hipStream_t stream)
{
    const float* features = (const float*)d_in[0];
    const float* pos      = (const float*)d_in[1];
    const float* refp     = (const float*)d_in[2];
    const float* W_off  = (const float*)d_in[5];
    const float* b_off  = (const float*)d_in[6];
    const float* W_attn = (const float*)d_in[7];
    const float* b_attn = (const float*)d_in[8];
    const float* W_val  = (const float*)d_in[9];
    const float* b_val  = (const float*)d_in[10];
    const float* W_out  = (const float*)d_in[11];
    const float* b_out  = (const float*)d_in[12];
    const float* ln1_g  = (const float*)d_in[13];
    const float* ln1_b  = (const float*)d_in[14];
    const float* W1     = (const float*)d_in[15];
    const float* b1     = (const float*)d_in[16];
    const float* W2     = (const float*)d_in[17];
    const float* b2     = (const float*)d_in[18];
    const float* ln2_g  = (const float*)d_in[19];
    const float* ln2_b  = (const float*)d_in[20];
    float* out = (float*)d_out;

    char* ws = (char*)d_ws;
    size_t o = 0;
    auto alloc = [&](size_t bytes) { char* p = ws + o; o += (bytes + 255) & ~(size_t)255; return p; };
    u16* Wt_val = (u16*)alloc((size_t)256 * 256 * 2);
    u16* Wt_oa  = (u16*)alloc((size_t)384 * 256 * 2);
    u16* Wt_out = (u16*)alloc((size_t)256 * 256 * 2);
    u16* W1f    = (u16*)alloc((size_t)1024 * 256 * 2);
    u16* W2f    = (u16*)alloc((size_t)256 * 1024 * 2);
    u16* qb     = (u16*)alloc((size_t)M_TOK * 256 * 2);   // q -> samp -> x (bf16)
    u16* fb     = (u16*)alloc((size_t)M_TOK * 256 * 2);   // features bf16
    char* big   = alloc((size_t)M_TOK * 1024 * 2);        // value|off_t|attn_t
    u16*   value = (u16*)big;
    float* offt  = (float*)(big + (size_t)M_TOK * 256 * 2);
    float* attnt = (float*)(big + (size_t)M_TOK * 256 * 2 + (size_t)M_TOK * 256 * 4);
    u16* samp = qb;
    u16* xb   = qb;

    dim3 blk(256);
    const int mb  = (M_TOK + 127) / 128;     // 416
    const int mb64 = (M_TOK + 63) / 64;      // 831

    prep_qf<<<2048, blk, 0, stream>>>(features, pos, qb, fb, M_TOK * 256 / 4);
    wtrans_all<<<2944, blk, 0, stream>>>(W_val, W_off, W_attn, W_out, W1, W2,
                                         Wt_val, Wt_oa, Wt_out, W1f, W2f);

    gemm128<MODE_VAL><<<dim3(mb, 2), blk, 0, stream>>>(
        fb, Wt_val, M_TOK, 256, b_val, nullptr, value, nullptr);
    gemm128<MODE_OFFATTN><<<dim3(mb, 3), blk, 0, stream>>>(
        qb, Wt_oa, M_TOK, 256, b_off, b_attn, offt, attnt);

    sample_kernel<<<6656, blk, 0, stream>>>(offt, attnt, value, refp, samp);

    // W_out GEMM + residual(features bf16) + LN1 -> xb (bf16)
    gemm_ln<4, 0><<<mb64, blk, 0, stream>>>(
        samp, Wt_out, b_out, fb, ln1_g, ln1_b, xb, nullptr, M_TOK);

    // fused FFN + residual + LN2 -> out (f32)
    ffn_fused<<<mb64, blk, 0, stream>>>(
        xb, W1f, W2f, b1, b2, ln2_g, ln2_b, out, M_TOK);
}